// Round 20
// baseline (267.831 us; speedup 1.0000x reference)
//
#include <hip/hip_runtime.h>

#define T_ 512
#define K_ 128
#define L2E 1.4426950408889634f
#define LN2 0.6931471805599453f

#if __has_builtin(__builtin_amdgcn_udot4)
#define DOT4(a, b, c) ((int)__builtin_amdgcn_udot4((unsigned)(a), (unsigned)(b), (unsigned)(c), false))
#define QMAXV 255
#elif __has_builtin(__builtin_amdgcn_sdot4)
#define DOT4(a, b, c) __builtin_amdgcn_sdot4((a), (b), (c), false)
#define QMAXV 127
#else
__device__ __forceinline__ int dot4_emu(int a, int b, int c) {
#pragma unroll
    for (int k = 0; k < 4; ++k)
        c += ((a >> (8 * k)) & 0xff) * ((b >> (8 * k)) & 0xff);
    return c;
}
#define DOT4(a, b, c) dot4_emu((a), (b), (c))
#define QMAXV 255
#endif

__device__ __forceinline__ int irl(int v, int lane) {
    return __builtin_amdgcn_readlane(v, lane);
}

// wave64 max-reduce step via DPP (pure VALU). values >= 0 so 0-fill safe.
#define DPPMAX(m, ctrl)                                                     \
    m = fmaxf(m, __int_as_float(__builtin_amdgcn_update_dpp(                 \
                     0, __float_as_int(m), (ctrl), 0xf, 0xf, true)))

// quad_perm [1,0,3,2]: swap even/odd neighbor lanes
#define DPP_SWAP(x) __builtin_amdgcn_update_dpp(0, (x), 0xB1, 0xf, 0xf, true)

// One step. u8 fixed-point, same-step exact-pow2 scale (proven R16 numerics,
// upgraded to full 8-bit band [128,255] via 2^(7-e)). Broadcast of the 32
// u-dwords via ds_bpermute (uniform index, VGPR->VGPR) instead of v_readlane:
// tests the SGPR-write-hazard theory for the ~4.8 cyc/instr solo-wave cadence.
#define BODY(tt, SLOT, SNEXT)                                                \
    {                                                                        \
        const int tc = ((tt) + 4 < len) ? (tt) + 4 : len - 1;                \
        SLOT = hb[(size_t)tc * 64];                                          \
        int a0 = 0, a1 = 0, a2 = 0, a3 = 0;                                  \
        int c0 = 0, c1 = 0, c2 = 0, c3 = 0;                                  \
        _Pragma("unroll")                                                    \
        for (int d = 0; d < 32; d += 4) {                                    \
            const int u0 = __builtin_amdgcn_ds_bpermute(bidx[d],     updw);  \
            const int u1 = __builtin_amdgcn_ds_bpermute(bidx[d + 1], updw);  \
            const int u2 = __builtin_amdgcn_ds_bpermute(bidx[d + 2], updw);  \
            const int u3 = __builtin_amdgcn_ds_bpermute(bidx[d + 3], updw);  \
            a0 = DOT4(Eq0[d],     u0, a0);  c0 = DOT4(Eq1[d],     u0, c0);   \
            a1 = DOT4(Eq0[d + 1], u1, a1);  c1 = DOT4(Eq1[d + 1], u1, c1);   \
            a2 = DOT4(Eq0[d + 2], u2, a2);  c2 = DOT4(Eq1[d + 2], u2, c2);   \
            a3 = DOT4(Eq0[d + 3], u3, a3);  c3 = DOT4(Eq1[d + 3], u3, c3);   \
        }                                                                    \
        const int acc0 = (a0 + a1) + (a2 + a3);                              \
        const int acc1 = (c0 + c1) + (c2 + c3);                              \
        const float vpre0 = (float)acc0 * ehc0;                              \
        const float vpre1 = (float)acc1 * ehc1;                              \
        float m_ = fmaxf(vpre0, vpre1);                                      \
        DPPMAX(m_, 0x111); DPPMAX(m_, 0x112); DPPMAX(m_, 0x114);             \
        DPPMAX(m_, 0x118); DPPMAX(m_, 0x142); DPPMAX(m_, 0x143);             \
        int e_ = (int)((unsigned)irl(__float_as_int(m_), 63) >> 23) - 127;   \
        e_ = max(e_, -20);                                                   \
        const float qs = __int_as_float((134 - e_) << 23); /* 2^(7-e) */     \
        CMi += e_ - 7;                                                       \
        int q0 = (int)fmaf(vpre0, qs, 0.5f);                                 \
        int q1 = (int)fmaf(vpre1, qs, 0.5f);                                 \
        q0 = min(q0, QMAXV);  q1 = min(q1, QMAXV);                           \
        qa = q0; qb = q1;                                                    \
        const int own16 = q0 | (q1 << 8);                                    \
        updw = own16 | (DPP_SWAP(own16) << 16);                              \
        ehc0 = exp2f((SNEXT).x * L2E) * rE0;                                 \
        ehc1 = exp2f((SNEXT).y * L2E) * rE1;                                 \
    }

// One wave per batch element. Lane l owns rows 2l, 2l+1.
__global__ __launch_bounds__(64)
__attribute__((amdgpu_waves_per_eu(1, 1)))
void crf_fwd(const float* __restrict__ h,
             const float* __restrict__ trans,
             const int* __restrict__ lengths,
             float* __restrict__ out)
{
    const int b  = blockIdx.x;
    const int l  = threadIdx.x;       // 0..63
    const int r0 = 2 * l, r1 = 2 * l + 1;

    // ---- one-time: opaque bpermute index regs (byte addr of even lanes).
    // asm keeps them in VGPRs so the compiler can't re-materialize per step.
    int bidx[32];
#pragma unroll
    for (int d = 0; d < 32; ++d)
        asm("v_mov_b32 %0, %1" : "=v"(bidx[d]) : "i"(8 * d));

    // ---- preamble pass 1: row maxima of E = exp(trans) ----
    const float4* ta = (const float4*)(trans + r0 * K_);
    const float4* tb = (const float4*)(trans + r1 * K_);
    float mx0 = 0.f, mx1 = 0.f;
#pragma unroll
    for (int q = 0; q < 32; ++q) {
        const float4 x = ta[q];
        mx0 = fmaxf(mx0, fmaxf(fmaxf(exp2f(x.x * L2E), exp2f(x.y * L2E)),
                               fmaxf(exp2f(x.z * L2E), exp2f(x.w * L2E))));
        const float4 y = tb[q];
        mx1 = fmaxf(mx1, fmaxf(fmaxf(exp2f(y.x * L2E), exp2f(y.y * L2E)),
                               fmaxf(exp2f(y.z * L2E), exp2f(y.w * L2E))));
    }
    mx0 = fmaxf(mx0, 1e-30f);
    mx1 = fmaxf(mx1, 1e-30f);
    const float sE0 = (float)QMAXV / mx0, sE1 = (float)QMAXV / mx1;
    const float rE0 = mx0 * (1.0f / (float)QMAXV);
    const float rE1 = mx1 * (1.0f / (float)QMAXV);

    // ---- preamble pass 2: quantize E rows to u8, pack 4/dword ----
    int Eq0[32], Eq1[32];
#pragma unroll
    for (int q = 0; q < 32; ++q) {
        const float4 x = ta[q];
        const int A0 = (int)(exp2f(x.x * L2E) * sE0 + 0.5f);
        const int A1 = (int)(exp2f(x.y * L2E) * sE0 + 0.5f);
        const int A2 = (int)(exp2f(x.z * L2E) * sE0 + 0.5f);
        const int A3 = (int)(exp2f(x.w * L2E) * sE0 + 0.5f);
        Eq0[q] = A0 | (A1 << 8) | (A2 << 16) | (A3 << 24);
        const float4 y = tb[q];
        const int C0 = (int)(exp2f(y.x * L2E) * sE1 + 0.5f);
        const int C1 = (int)(exp2f(y.y * L2E) * sE1 + 0.5f);
        const int C2 = (int)(exp2f(y.z * L2E) * sE1 + 0.5f);
        const int C3 = (int)(exp2f(y.w * L2E) * sE1 + 0.5f);
        Eq1[q] = C0 | (C1 << 8) | (C2 << 16) | (C3 << 24);
    }

    const int len = lengths[b];
    const float2* hb = (const float2*)(h + (size_t)b * (T_ * K_) + r0);

    // state: one-hot at START=127 -> q[127]=128, CMi=-7 (128*2^-7 = 1)
    int qa = 0, qb = (l == 63) ? 128 : 0;
    int CMi = -7;
    int updw;
    {
        const int own16 = qa | (qb << 8);
        updw = own16 | (DPP_SWAP(own16) << 16);
    }

    float2 s0 = hb[0];
    float2 s1 = hb[(size_t)((1 < len) ? 1 : len - 1) * 64];
    float2 s2 = hb[(size_t)((2 < len) ? 2 : len - 1) * 64];
    float2 s3 = hb[(size_t)((3 < len) ? 3 : len - 1) * 64];
    float ehc0 = exp2f(s0.x * L2E) * rE0;
    float ehc1 = exp2f(s0.y * L2E) * rE1;

    int t = 0;
    const int nfull = len & ~3;
    for (; t < nfull; t += 4) {
        BODY(t + 0, s0, s1);
        BODY(t + 1, s1, s2);
        BODY(t + 2, s2, s3);
        BODY(t + 3, s3, s0);
    }
    if (t     < len) BODY(t,     s0, s1);
    if (t + 1 < len) BODY(t + 1, s1, s2);
    if (t + 2 < len) BODY(t + 2, s2, s3);

    // ---- out[b] = ln2 * (CMi + log2( sum_i q_i * exp(trans[END,i]) )) ----
    const float tEa = exp2f(trans[(K_ - 2) * K_ + r0] * L2E);
    const float tEb = exp2f(trans[(K_ - 2) * K_ + r1] * L2E);
    float s = (float)qa * tEa + (float)qb * tEb;
#pragma unroll
    for (int off = 32; off >= 1; off >>= 1)
        s += __shfl_xor(s, off, 64);
    if (l == 0) out[b] = ((float)CMi + log2f(s)) * LN2;
}

extern "C" void kernel_launch(void* const* d_in, const int* in_sizes, int n_in,
                              void* d_out, int out_size, void* d_ws, size_t ws_size,
                              hipStream_t stream) {
    const float* h       = (const float*)d_in[0];
    const float* trans   = (const float*)d_in[1];
    const int*   lengths = (const int*)d_in[2];
    float*       out     = (float*)d_out;
    const int B = in_sizes[2];   // 512
    crf_fwd<<<B, 64, 0, stream>>>(h, trans, lengths, out);
}

// Round 23
// 169.537 us; speedup vs baseline: 1.5798x; 1.5798x over previous
//
#include <hip/hip_runtime.h>

#define T_ 512
#define K_ 128
#define L2E 1.4426950408889634f
#define LN2 0.6931471805599453f

__device__ __forceinline__ int irl(int v, int lane) {
    return __builtin_amdgcn_readlane(v, lane);
}

#if __has_builtin(__builtin_amdgcn_udot4)
#define DOT4(a, b, c) ((int)__builtin_amdgcn_udot4((unsigned)(a), (unsigned)(b), (unsigned)(c), false))
#elif __has_builtin(__builtin_amdgcn_sdot4)
#define DOT4(a, b, c) __builtin_amdgcn_sdot4((a), (b), (c), false)
#else
__device__ __forceinline__ int dot4_emu(int a, int b, int c) {
#pragma unroll
    for (int k = 0; k < 4; ++k)
        c += ((a >> (8 * k)) & 0xff) * ((b >> (8 * k)) & 0xff);
    return c;
}
#define DOT4(a, b, c) dot4_emu((a), (b), (c))
#endif

#if __has_builtin(__builtin_amdgcn_udot8)
#define DOT8(a, b, c) ((int)__builtin_amdgcn_udot8((unsigned)(a), (unsigned)(b), (unsigned)(c), false))
#else
__device__ __forceinline__ int dot8_emu(int a, int b, int c) {
    const int al = a & 0x0F0F0F0F, ah = (int)(((unsigned)a >> 4) & 0x0F0F0F0F);
    const int bl = b & 0x0F0F0F0F, bh = (int)(((unsigned)b >> 4) & 0x0F0F0F0F);
    return DOT4(ah, bh, DOT4(al, bl, c));
}
#define DOT8(a, b, c) dot8_emu((a), (b), (c))
#endif

// wave64 max-reduce step via DPP (pure VALU). values >= 0 so 0-fill safe.
#define DPPMAX(m, ctrl)                                                     \
    m = fmaxf(m, __int_as_float(__builtin_amdgcn_update_dpp(                 \
                     0, __float_as_int(m), (ctrl), 0xf, 0xf, true)))

#define DPP_Q1(x) __builtin_amdgcn_update_dpp(0, (x), 0xB1, 0xf, 0xf, true) // [1,0,3,2]
#define DPP_Q2(x) __builtin_amdgcn_update_dpp(0, (x), 0x4E, 0xf, 0xf, true) // [2,3,0,1]

// One step, u4 fixed-point (R18 numerics, bit-identical). Same-step exact
// pow2 scale 2^(3-e), band [8,15] (proven safe vs the END-state trap that
// killed every lag-1 variant). Tail trims vs R18: gather levels are
// shift->DPP->OR (2 deps vs 3), folds grouped for v_add3.
#define BODY(tt, SLOT, SNEXT)                                                \
    {                                                                        \
        const int tc = ((tt) + 4 < len) ? (tt) + 4 : len - 1;                \
        SLOT = hb[(size_t)tc * 64];                                          \
        int a0 = 0, a1 = 0, a2 = 0, a3 = 0;                                  \
        int c0 = 0, c1 = 0, c2 = 0, c3 = 0;                                  \
        _Pragma("unroll")                                                    \
        for (int d = 0; d < 16; d += 4) {                                    \
            const int u0 = irl(updw, 4 * d);                                 \
            const int u1 = irl(updw, 4 * d + 4);                             \
            const int u2 = irl(updw, 4 * d + 8);                             \
            const int u3 = irl(updw, 4 * d + 12);                            \
            a0 = DOT8(Eq0[d],     u0, a0);  c0 = DOT8(Eq1[d],     u0, c0);   \
            a1 = DOT8(Eq0[d + 1], u1, a1);  c1 = DOT8(Eq1[d + 1], u1, c1);   \
            a2 = DOT8(Eq0[d + 2], u2, a2);  c2 = DOT8(Eq1[d + 2], u2, c2);   \
            a3 = DOT8(Eq0[d + 3], u3, a3);  c3 = DOT8(Eq1[d + 3], u3, c3);   \
        }                                                                    \
        const int acc0 = ((a0 + a1) + a2) + a3;   /* add3-friendly */        \
        const int acc1 = ((c0 + c1) + c2) + c3;                              \
        const float vpre0 = (float)acc0 * ehp0;                              \
        const float vpre1 = (float)acc1 * ehp1;                              \
        float m_ = fmaxf(vpre0, vpre1);                                      \
        DPPMAX(m_, 0x111); DPPMAX(m_, 0x112); DPPMAX(m_, 0x114);             \
        DPPMAX(m_, 0x118); DPPMAX(m_, 0x142); DPPMAX(m_, 0x143);             \
        const int e_ = (int)((unsigned)irl(__float_as_int(m_), 63) >> 23) - 127; \
        const float qs = __int_as_float((130 - e_) << 23); /* 2^(3-e) */     \
        CMi += e_ - 3;                                                       \
        int q0 = (int)fmaf(vpre0, qs, 0.5f);                                 \
        int q1 = (int)fmaf(vpre1, qs, 0.5f);                                 \
        q0 = min(q0, 15);  q1 = min(q1, 15);                                 \
        qa = q0; qb = q1;                                                    \
        /* gather: shifted-OR levels (2 serial deps per level) */            \
        const int sb = (q0 | (q1 << 4)) << sh1;                              \
        const int h16 = sb | DPP_Q1(sb);                                     \
        const int sw = h16 << sh2;                                           \
        updw = sw | DPP_Q2(sw);                                              \
        ehp0 = exp2f(fmaf((SNEXT).x, L2E, lrE0));                            \
        ehp1 = exp2f(fmaf((SNEXT).y, L2E, lrE1));                            \
    }

// One wave per batch element. Lane l owns rows 2l, 2l+1. u4 matvec:
// 16 readlane + 32 udot8 in 8 independent chains.
__global__ __launch_bounds__(64)
__attribute__((amdgpu_waves_per_eu(1, 1)))
void crf_fwd(const float* __restrict__ h,
             const float* __restrict__ trans,
             const int* __restrict__ lengths,
             float* __restrict__ out)
{
    const int b  = blockIdx.x;
    const int l  = threadIdx.x;       // 0..63
    const int r0 = 2 * l, r1 = 2 * l + 1;
    const int sh1 = 8 * (l & 1);           // byte slot within pair
    const int sh2 = 16 * ((l >> 1) & 1);   // half slot within quad

    // ---- preamble pass 1: row maxima of E = exp(trans) ----
    const float4* ta = (const float4*)(trans + r0 * K_);
    const float4* tb = (const float4*)(trans + r1 * K_);
    float mx0 = 0.f, mx1 = 0.f;
#pragma unroll
    for (int q = 0; q < 32; ++q) {
        const float4 x = ta[q];
        mx0 = fmaxf(mx0, fmaxf(fmaxf(exp2f(x.x * L2E), exp2f(x.y * L2E)),
                               fmaxf(exp2f(x.z * L2E), exp2f(x.w * L2E))));
        const float4 y = tb[q];
        mx1 = fmaxf(mx1, fmaxf(fmaxf(exp2f(y.x * L2E), exp2f(y.y * L2E)),
                               fmaxf(exp2f(y.z * L2E), exp2f(y.w * L2E))));
    }
    mx0 = fmaxf(mx0, 1e-30f);
    mx1 = fmaxf(mx1, 1e-30f);
    const float sE0 = 15.0f / mx0, sE1 = 15.0f / mx1;
    const float lrE0 = log2f(mx0 * (1.0f / 15.0f));
    const float lrE1 = log2f(mx1 * (1.0f / 15.0f));

    // ---- preamble pass 2: quantize E rows to u4, pack 8 nibbles/dword ----
    int Eq0[16], Eq1[16];
#pragma unroll
    for (int q = 0; q < 16; ++q) {
        const float4 x = ta[2 * q], x2 = ta[2 * q + 1];
        int w = 0;
        w |= (int)(exp2f(x.x  * L2E) * sE0 + 0.5f);
        w |= (int)(exp2f(x.y  * L2E) * sE0 + 0.5f) << 4;
        w |= (int)(exp2f(x.z  * L2E) * sE0 + 0.5f) << 8;
        w |= (int)(exp2f(x.w  * L2E) * sE0 + 0.5f) << 12;
        w |= (int)(exp2f(x2.x * L2E) * sE0 + 0.5f) << 16;
        w |= (int)(exp2f(x2.y * L2E) * sE0 + 0.5f) << 20;
        w |= (int)(exp2f(x2.z * L2E) * sE0 + 0.5f) << 24;
        w |= (int)(exp2f(x2.w * L2E) * sE0 + 0.5f) << 28;
        Eq0[q] = w;
        const float4 y = tb[2 * q], y2 = tb[2 * q + 1];
        int v = 0;
        v |= (int)(exp2f(y.x  * L2E) * sE1 + 0.5f);
        v |= (int)(exp2f(y.y  * L2E) * sE1 + 0.5f) << 4;
        v |= (int)(exp2f(y.z  * L2E) * sE1 + 0.5f) << 8;
        v |= (int)(exp2f(y.w  * L2E) * sE1 + 0.5f) << 12;
        v |= (int)(exp2f(y2.x * L2E) * sE1 + 0.5f) << 16;
        v |= (int)(exp2f(y2.y * L2E) * sE1 + 0.5f) << 20;
        v |= (int)(exp2f(y2.z * L2E) * sE1 + 0.5f) << 24;
        v |= (int)(exp2f(y2.w * L2E) * sE1 + 0.5f) << 28;
        Eq1[q] = v;
    }

    const int len = lengths[b];
    const float2* hb = (const float2*)(h + (size_t)b * (T_ * K_) + r0);

    // state: one-hot at START=127 -> q[127]=8 (true 1 = 8*2^-3), CMi=-3
    int qa = 0, qb = (l == 63) ? 8 : 0;
    int CMi = -3;
    int updw;
    {
        const int sb = (qa | (qb << 4)) << sh1;
        const int h16 = sb | DPP_Q1(sb);
        const int sw = h16 << sh2;
        updw = sw | DPP_Q2(sw);
    }

    float2 s0 = hb[0];
    float2 s1 = hb[(size_t)((1 < len) ? 1 : len - 1) * 64];
    float2 s2 = hb[(size_t)((2 < len) ? 2 : len - 1) * 64];
    float2 s3 = hb[(size_t)((3 < len) ? 3 : len - 1) * 64];
    float ehp0 = exp2f(fmaf(s0.x, L2E, lrE0));
    float ehp1 = exp2f(fmaf(s0.y, L2E, lrE1));

    int t = 0;
    const int nfull = len & ~3;
    for (; t < nfull; t += 4) {
        BODY(t + 0, s0, s1);
        BODY(t + 1, s1, s2);
        BODY(t + 2, s2, s3);
        BODY(t + 3, s3, s0);
    }
    if (t     < len) BODY(t,     s0, s1);
    if (t + 1 < len) BODY(t + 1, s1, s2);
    if (t + 2 < len) BODY(t + 2, s2, s3);

    // ---- out[b] = ln2 * (CMi + log2( sum_i q_i * exp(trans[END,i]) )) ----
    const float tEa = exp2f(trans[(K_ - 2) * K_ + r0] * L2E);
    const float tEb = exp2f(trans[(K_ - 2) * K_ + r1] * L2E);
    float s = (float)qa * tEa + (float)qb * tEb;
#pragma unroll
    for (int off = 32; off >= 1; off >>= 1)
        s += __shfl_xor(s, off, 64);
    if (l == 0) out[b] = ((float)CMi + log2f(s)) * LN2;
}

extern "C" void kernel_launch(void* const* d_in, const int* in_sizes, int n_in,
                              void* d_out, int out_size, void* d_ws, size_t ws_size,
                              hipStream_t stream) {
    const float* h       = (const float*)d_in[0];
    const float* trans   = (const float*)d_in[1];
    const int*   lengths = (const int*)d_in[2];
    float*       out     = (float*)d_out;
    const int B = in_sizes[2];   // 512
    crf_fwd<<<B, 64, 0, stream>>>(h, trans, lengths, out);
}